// Round 9
// baseline (112.847 us; speedup 1.0000x reference)
//
#include <hip/hip_runtime.h>
#include <hip/hip_bf16.h>

#define WT0 (-0.09375f)
#define WT1 (0.59375f)

typedef float f4v __attribute__((ext_vector_type(4)));
typedef float f2v __attribute__((ext_vector_type(2)));

// ---------------------------------------------------------------------------
// Bilateral-loss tile core. Tile = (64*PX) x 4 px, 256 threads, PX px/thread.
// rw loads are nontemporal (streamed once); f/h come from the LDS halo tile.
// Per-thread neighborhood needs exactly PX+4 columns (taps dj+p, dj<5, p<PX).
// ---------------------------------------------------------------------------
template <int S, int PX>
__device__ __forceinline__ float bilat_tile(
    const float* __restrict__ Fb, const float* __restrict__ Hb,
    const float* __restrict__ rwB,           // rw + b*25*S*S
    float* __restrict__ sf, float* __restrict__ sh,
    const float* __restrict__ swin,
    int bx0, int by0, int tid)
{
    constexpr int TW = 64 * PX;
    constexpr int LW = TW + 4;
    const int tx = tid & 63, ty = tid >> 6;

    for (int i = tid; i < 8 * LW; i += 256) {
        const int r = i / LW, c = i % LW;
        const int y = by0 + r - 2, x = bx0 + c - 2;
        float fv = 0.f, hv = 0.f;
        if ((unsigned)y < (unsigned)S && (unsigned)x < (unsigned)S) {
            const size_t id = (size_t)y * S + x;
            fv = Fb[id]; hv = Hb[id];
        }
        sf[r * LW + c] = fv; sh[r * LW + c] = hv;
    }
    __syncthreads();

    const int x0 = bx0 + PX * tx, y = by0 + ty;
    const size_t ks = (size_t)S * S;
    const float* rwp = rwB + (size_t)y * S + x0;

    float wsum[PX], fs[PX], hs[PX];
#pragma unroll
    for (int p = 0; p < PX; ++p) { wsum[p] = 0.f; fs[p] = 0.f; hs[p] = 0.f; }

#pragma unroll
    for (int di = 0; di < 5; ++di) {
        float f9[PX + 4], h9[PX + 4];   // exactly PX+4 used; do NOT read past
        const int ro = (ty + di) * LW + PX * tx;
        if constexpr (PX == 4) {
            const f4v a0 = *(const f4v*)&sf[ro], a1 = *(const f4v*)&sf[ro + 4];
            f9[0]=a0[0]; f9[1]=a0[1]; f9[2]=a0[2]; f9[3]=a0[3];
            f9[4]=a1[0]; f9[5]=a1[1]; f9[6]=a1[2]; f9[7]=a1[3];
            const f4v b0 = *(const f4v*)&sh[ro], b1 = *(const f4v*)&sh[ro + 4];
            h9[0]=b0[0]; h9[1]=b0[1]; h9[2]=b0[2]; h9[3]=b0[3];
            h9[4]=b1[0]; h9[5]=b1[1]; h9[6]=b1[2]; h9[7]=b1[3];
        } else if constexpr (PX == 2) {
            const f2v a0 = *(const f2v*)&sf[ro], a1 = *(const f2v*)&sf[ro + 2],
                      a2 = *(const f2v*)&sf[ro + 4];
            f9[0]=a0[0]; f9[1]=a0[1]; f9[2]=a1[0]; f9[3]=a1[1]; f9[4]=a2[0]; f9[5]=a2[1];
            const f2v b0 = *(const f2v*)&sh[ro], b1 = *(const f2v*)&sh[ro + 2],
                      b2 = *(const f2v*)&sh[ro + 4];
            h9[0]=b0[0]; h9[1]=b0[1]; h9[2]=b1[0]; h9[3]=b1[1]; h9[4]=b2[0]; h9[5]=b2[1];
        } else {
#pragma unroll
            for (int j = 0; j < 5; ++j) { f9[j] = sf[ro + j]; h9[j] = sh[ro + j]; }
        }
#pragma unroll
        for (int dj = 0; dj < 5; ++dj) {
            const int k = di * 5 + dj;
            float rv[PX];
            if constexpr (PX == 4) {
                const f4v t4 = __builtin_nontemporal_load((const f4v*)(rwp + (size_t)k * ks));
                rv[0]=t4[0]; rv[1]=t4[1]; rv[2]=t4[2]; rv[3]=t4[3];
            } else if constexpr (PX == 2) {
                const f2v t2 = __builtin_nontemporal_load((const f2v*)(rwp + (size_t)k * ks));
                rv[0]=t2[0]; rv[1]=t2[1];
            } else {
                rv[0] = __builtin_nontemporal_load(rwp + (size_t)k * ks);
            }
#pragma unroll
            for (int p = 0; p < PX; ++p) {
                const float wm = swin[k] * rv[p];
                wsum[p] += wm;
                fs[p] = fmaf(wm, f9[dj + p], fs[p]);
                hs[p] = fmaf(wm, h9[dj + p], hs[p]);
            }
        }
    }
    float v = 0.f;
#pragma unroll
    for (int p = 0; p < PX; ++p) {
        const float d = (fs[p] - hs[p]) / wsum[p];
        v = fmaf(d, d, v);
    }
    return v;
}

__device__ __forceinline__ void reduce_and_store(
    float v, float scale, int tid, float* wred, double* slot)
{
#pragma unroll
    for (int off = 32; off > 0; off >>= 1) v += __shfl_down(v, off, 64);
    if ((tid & 63) == 0) wred[tid >> 6] = v;
    __syncthreads();
    if (tid == 0) {
        const float s = wred[0] + wred[1] + wred[2] + wred[3];
        *slot = (double)s * (double)scale;
    }
}

// ---------------------------------------------------------------------------
// Loss (level k) + fused bicubic/2 build of the level-(k+1) images from the
// LDS halo tile (edge-clamped taps never touch the zero-pad cells).
// ---------------------------------------------------------------------------
template <int S, int PX, int MINW>
__global__ __launch_bounds__(256, MINW) void loss_down_kernel(
    const float* __restrict__ F0, const float* __restrict__ H0,
    const float* __restrict__ window, const float* __restrict__ RW,
    double* __restrict__ slots, float scale,
    float* __restrict__ fd, float* __restrict__ hd)
{
    constexpr int TW = 64 * PX, LW = TW + 4;
    __shared__ __align__(16) float sf[8 * LW];
    __shared__ __align__(16) float sh[8 * LW];
    __shared__ float swin[25];
    __shared__ float wred[4];

    const int tid = threadIdx.x;
    if (tid < 25) swin[tid] = window[tid];

    constexpr int tilesX = S / TW, tilesY = S / 4, per = tilesX * tilesY;
    const int lin = blockIdx.x;
    const int b = lin / per, q = lin % per;
    const int bx0 = (q % tilesX) * TW, by0 = (q / tilesX) * 4;

    const float v = bilat_tile<S, PX>(
        F0 + (size_t)b * S * S, H0 + (size_t)b * S * S,
        RW + (size_t)b * 25 * S * S, sf, sh, swin, bx0, by0, tid);

    // fused /2 downsample: 2 rows x TW/2 cols per image
    {
        constexpr int Sh = S / 2;
        const float wt[4] = {WT0, WT1, WT1, WT0};
        float* const fdb = fd + (size_t)b * Sh * Sh;
        float* const hdb = hd + (size_t)b * Sh * Sh;
        for (int i = tid; i < 2 * TW; i += 256) {
            const int img = i / TW, t2 = i % TW;
            const int r = t2 / (TW / 2), c = t2 % (TW / 2);
            const float* s = img ? sh : sf;
            int lc[4];
#pragma unroll
            for (int kx = 0; kx < 4; ++kx)
                lc[kx] = min(max(bx0 + 2 * c - 1 + kx, 0), S - 1) - bx0 + 2;
            float acc = 0.f;
#pragma unroll
            for (int ky = 0; ky < 4; ++ky) {
                const int lr = min(max(by0 + 2 * r - 1 + ky, 0), S - 1) - by0 + 2;
                const float rs = WT0 * (s[lr * LW + lc[0]] + s[lr * LW + lc[3]])
                               + WT1 * (s[lr * LW + lc[1]] + s[lr * LW + lc[2]]);
                acc = fmaf(wt[ky], rs, acc);
            }
            (img ? hdb : fdb)[((size_t)((by0 >> 1) + r)) * Sh + ((bx0 >> 1) + c)] = acc;
        }
    }

    reduce_and_store(v, scale, tid, wred, &slots[lin]);
}

// ---------------------------------------------------------------------------
// Tail: level-2 loss (512 blocks, tile 64x4 from f2) + level-3 loss
// (128 blocks, L3 tile rebuilt locally from f2 -> no global f3).
// ---------------------------------------------------------------------------
__global__ __launch_bounds__(256, 4) void loss_tail_kernel(
    const float* __restrict__ window,
    const float* __restrict__ rw2, const float* __restrict__ rw3,
    const float* __restrict__ f2, const float* __restrict__ h2,
    double* __restrict__ slots)
{
    __shared__ float smem[5696];   // union: L2 loss 2*544 | L3: p2 4608 + l3 1088
    __shared__ float swin[25];
    __shared__ float wred[4];

    const int tid = threadIdx.x;
    const int tx = tid & 63, ty = tid >> 6;
    if (tid < 25) swin[tid] = window[tid];
    const int lin = blockIdx.x;

    float v, scale;
    if (lin < 512) {
        // level 2: S=128, tile 64x4, PX=1
        const int b = lin >> 6, q = lin & 63;
        const int bx0 = (q & 1) * 64, by0 = (q >> 1) * 4;
        v = bilat_tile<128, 1>(
            f2 + (size_t)b * 16384, h2 + (size_t)b * 16384,
            rw2 + (size_t)b * 25 * 16384,
            smem, smem + 544, swin, bx0, by0, tid);
        scale = 0.25f / (8.f * 128.f * 128.f);
    } else {
        // level 3: S=64, tile 64x4; rebuild L3 tile from f2/h2 in LDS
        const int t = lin - 512;
        const int b = t >> 4, by0 = (t & 15) * 4;
        float* p2 = smem;          // [2][18][128]
        float* l3 = smem + 4608;   // [2][8][68]
        const int fr0 = 2 * by0 - 5;
        for (int i = tid; i < 2 * 18 * 128; i += 256) {
            const int img = i / 2304, j = i % 2304;
            const int r = j >> 7, c = j & 127;
            const int gy = min(max(fr0 + r, 0), 127);
            p2[i] = (img ? h2 : f2)[((size_t)b * 128 + gy) * 128 + c];
        }
        __syncthreads();
        const float wt[4] = {WT0, WT1, WT1, WT0};
        for (int i = tid; i < 2 * 8 * 68; i += 256) {
            const int img = i / 544, j = i % 544;
            const int r = j / 68, c = j % 68;
            const int gy = by0 - 2 + r, gx = c - 2;
            float a = 0.f;
            if ((unsigned)gy < 64u && (unsigned)gx < 64u) {
                int ry[4], cx[4];
#pragma unroll
                for (int k = 0; k < 4; ++k) {
                    ry[k] = min(max(2 * gy - 1 + k, 0), 127) - fr0;
                    cx[k] = min(max(2 * gx - 1 + k, 0), 127);
                }
#pragma unroll
                for (int ky = 0; ky < 4; ++ky) {
                    const float* row = p2 + img * 2304 + ry[ky] * 128;
                    const float rs = WT0 * (row[cx[0]] + row[cx[3]])
                                   + WT1 * (row[cx[1]] + row[cx[2]]);
                    a = fmaf(wt[ky], rs, a);
                }
            }
            l3[i] = a;
        }
        __syncthreads();

        const size_t ks = 64 * 64;
        const float* rwp = rw3 + (size_t)b * 25 * ks + (size_t)(by0 + ty) * 64 + tx;
        float wsum = 0.f, fsv = 0.f, hsv = 0.f;
#pragma unroll
        for (int di = 0; di < 5; ++di) {
#pragma unroll
            for (int dj = 0; dj < 5; ++dj) {
                const int k = di * 5 + dj;
                const float wm = swin[k] * __builtin_nontemporal_load(rwp + (size_t)k * ks);
                wsum += wm;
                fsv = fmaf(wm, l3[0 * 544 + (ty + di) * 68 + (tx + dj)], fsv);
                hsv = fmaf(wm, l3[1 * 544 + (ty + di) * 68 + (tx + dj)], hsv);
            }
        }
        const float d = (fsv - hsv) / wsum;
        v = d * d;
        scale = 0.125f / (8.f * 64.f * 64.f);
    }

    reduce_and_store(v, scale, tid, wred, &slots[lin]);
}

__global__ void finalize_kernel(const double* __restrict__ slots, float* __restrict__ out, int n)
{
    __shared__ double dred[4];
    const int t = threadIdx.x;  // 256 threads
    double s = 0.0;
    for (int i = t; i < n; i += 256) s += slots[i];
#pragma unroll
    for (int off = 32; off > 0; off >>= 1) s += __shfl_down(s, off, 64);
    if ((t & 63) == 0) dred[t >> 6] = s;
    __syncthreads();
    if (t == 0) out[0] = (float)(dred[0] + dred[1] + dred[2] + dred[3]);
}

extern "C" void kernel_launch(void* const* d_in, const int* in_sizes, int n_in,
                              void* d_out, int out_size, void* d_ws, size_t ws_size,
                              hipStream_t stream)
{
    const float* fake   = (const float*)d_in[0];
    const float* hdr    = (const float*)d_in[1];
    const float* window = (const float*)d_in[2];
    const float* rw0    = (const float*)d_in[3];
    const float* rw1    = (const float*)d_in[4];
    const float* rw2    = (const float*)d_in[5];
    const float* rw3    = (const float*)d_in[6];
    float* out = (float*)d_out;

    const int B = 8;
    char* ws = (char*)d_ws;
    double* slots = (double*)ws;                 // 3712 doubles, all stored each call
    float* f1 = (float*)(ws + 32768);
    const size_t n1 = (size_t)B * 256 * 256;
    float* h1 = f1 + n1;
    float* f2 = h1 + n1;
    const size_t n2 = (size_t)B * 128 * 128;
    float* h2 = f2 + n2;

    // K1: level-0 loss + f1 build. 2048 blocks, tile 256x4, PX=4.
    loss_down_kernel<512, 4, 1><<<dim3(2048), 256, 0, stream>>>(
        fake, hdr, window, rw0, slots, 1.0f / (8.f * 512.f * 512.f), f1, h1);

    // K2: level-1 loss + f2 build. 1024 blocks, tile 128x4, PX=2, 8 wg/CU.
    loss_down_kernel<256, 2, 8><<<dim3(1024), 256, 0, stream>>>(
        f1, h1, window, rw1, slots + 2048, 0.5f / (8.f * 256.f * 256.f), f2, h2);

    // K3: level-2 (512) + level-3 rebuild (128).
    loss_tail_kernel<<<dim3(640), 256, 0, stream>>>(
        window, rw2, rw3, f2, h2, slots + 3072);

    // K4: final reduction of 3712 slots.
    finalize_kernel<<<1, 256, 0, stream>>>(slots, out, 3712);
}

// Round 10
// 89.498 us; speedup vs baseline: 1.2609x; 1.2609x over previous
//
#include <hip/hip_runtime.h>
#include <hip/hip_bf16.h>

#define WT0 (-0.09375f)
#define WT1 (0.59375f)

typedef float f4v __attribute__((ext_vector_type(4)));
typedef float f2v __attribute__((ext_vector_type(2)));

// ---------------------------------------------------------------------------
// Bilateral-loss tile core. Tile = (64*PX) x 4 px, 256 threads, PX px/thread.
// Plain vector loads for rw (nontemporal hurt: R9 112us vs R6 70us — nt
// bypasses L2 allocation and broke streaming fetch efficiency).
// ---------------------------------------------------------------------------
template <int S, int PX>
__device__ __forceinline__ float bilat_tile(
    const float* __restrict__ Fb, const float* __restrict__ Hb,
    const float* __restrict__ rwB,           // rw + b*25*S*S
    float* __restrict__ sf, float* __restrict__ sh,
    const float* __restrict__ swin,
    int bx0, int by0, int tid)
{
    constexpr int TW = 64 * PX;
    constexpr int LW = TW + 4;
    const int tx = tid & 63, ty = tid >> 6;

    for (int i = tid; i < 8 * LW; i += 256) {
        const int r = i / LW, c = i % LW;
        const int y = by0 + r - 2, x = bx0 + c - 2;
        float fv = 0.f, hv = 0.f;
        if ((unsigned)y < (unsigned)S && (unsigned)x < (unsigned)S) {
            const size_t id = (size_t)y * S + x;
            fv = Fb[id]; hv = Hb[id];
        }
        sf[r * LW + c] = fv; sh[r * LW + c] = hv;
    }
    __syncthreads();

    const int x0 = bx0 + PX * tx, y = by0 + ty;
    const size_t ks = (size_t)S * S;
    const float* rwp = rwB + (size_t)y * S + x0;

    float wsum[PX], fs[PX], hs[PX];
#pragma unroll
    for (int p = 0; p < PX; ++p) { wsum[p] = 0.f; fs[p] = 0.f; hs[p] = 0.f; }

#pragma unroll
    for (int di = 0; di < 5; ++di) {
        float f9[PX + 4], h9[PX + 4];   // exactly PX+4 used; do NOT read past
        const int ro = (ty + di) * LW + PX * tx;
        if constexpr (PX == 4) {
            const f4v a0 = *(const f4v*)&sf[ro], a1 = *(const f4v*)&sf[ro + 4];
            f9[0]=a0[0]; f9[1]=a0[1]; f9[2]=a0[2]; f9[3]=a0[3];
            f9[4]=a1[0]; f9[5]=a1[1]; f9[6]=a1[2]; f9[7]=a1[3];
            const f4v b0 = *(const f4v*)&sh[ro], b1 = *(const f4v*)&sh[ro + 4];
            h9[0]=b0[0]; h9[1]=b0[1]; h9[2]=b0[2]; h9[3]=b0[3];
            h9[4]=b1[0]; h9[5]=b1[1]; h9[6]=b1[2]; h9[7]=b1[3];
        } else if constexpr (PX == 2) {
            const f2v a0 = *(const f2v*)&sf[ro], a1 = *(const f2v*)&sf[ro + 2],
                      a2 = *(const f2v*)&sf[ro + 4];
            f9[0]=a0[0]; f9[1]=a0[1]; f9[2]=a1[0]; f9[3]=a1[1]; f9[4]=a2[0]; f9[5]=a2[1];
            const f2v b0 = *(const f2v*)&sh[ro], b1 = *(const f2v*)&sh[ro + 2],
                      b2 = *(const f2v*)&sh[ro + 4];
            h9[0]=b0[0]; h9[1]=b0[1]; h9[2]=b1[0]; h9[3]=b1[1]; h9[4]=b2[0]; h9[5]=b2[1];
        } else {
#pragma unroll
            for (int j = 0; j < 5; ++j) { f9[j] = sf[ro + j]; h9[j] = sh[ro + j]; }
        }
#pragma unroll
        for (int dj = 0; dj < 5; ++dj) {
            const int k = di * 5 + dj;
            float rv[PX];
            if constexpr (PX == 4) {
                const f4v t4 = *(const f4v*)(rwp + (size_t)k * ks);
                rv[0]=t4[0]; rv[1]=t4[1]; rv[2]=t4[2]; rv[3]=t4[3];
            } else if constexpr (PX == 2) {
                const f2v t2 = *(const f2v*)(rwp + (size_t)k * ks);
                rv[0]=t2[0]; rv[1]=t2[1];
            } else {
                rv[0] = rwp[(size_t)k * ks];
            }
#pragma unroll
            for (int p = 0; p < PX; ++p) {
                const float wm = swin[k] * rv[p];
                wsum[p] += wm;
                fs[p] = fmaf(wm, f9[dj + p], fs[p]);
                hs[p] = fmaf(wm, h9[dj + p], hs[p]);
            }
        }
    }
    float v = 0.f;
#pragma unroll
    for (int p = 0; p < PX; ++p) {
        const float d = (fs[p] - hs[p]) / wsum[p];
        v = fmaf(d, d, v);
    }
    return v;
}

__device__ __forceinline__ void reduce_and_store(
    float v, float scale, int tid, float* wred, double* slot)
{
#pragma unroll
    for (int off = 32; off > 0; off >>= 1) v += __shfl_down(v, off, 64);
    if ((tid & 63) == 0) wred[tid >> 6] = v;
    __syncthreads();
    if (tid == 0) {
        const float s = wred[0] + wred[1] + wred[2] + wred[3];
        *slot = (double)s * (double)scale;
    }
}

// ---------------------------------------------------------------------------
// Loss (level k) + fused bicubic/2 build of the level-(k+1) images from the
// LDS halo tile (edge-clamped taps never touch the zero-pad cells).
// ---------------------------------------------------------------------------
template <int S, int PX, int MINW>
__global__ __launch_bounds__(256, MINW) void loss_down_kernel(
    const float* __restrict__ F0, const float* __restrict__ H0,
    const float* __restrict__ window, const float* __restrict__ RW,
    double* __restrict__ slots, float scale,
    float* __restrict__ fd, float* __restrict__ hd)
{
    constexpr int TW = 64 * PX, LW = TW + 4;
    __shared__ __align__(16) float sf[8 * LW];
    __shared__ __align__(16) float sh[8 * LW];
    __shared__ float swin[25];
    __shared__ float wred[4];

    const int tid = threadIdx.x;
    if (tid < 25) swin[tid] = window[tid];

    constexpr int tilesX = S / TW, tilesY = S / 4, per = tilesX * tilesY;
    const int lin = blockIdx.x;
    const int b = lin / per, q = lin % per;
    const int bx0 = (q % tilesX) * TW, by0 = (q / tilesX) * 4;

    const float v = bilat_tile<S, PX>(
        F0 + (size_t)b * S * S, H0 + (size_t)b * S * S,
        RW + (size_t)b * 25 * S * S, sf, sh, swin, bx0, by0, tid);

    // fused /2 downsample: 2 rows x TW/2 cols per image
    {
        constexpr int Sh = S / 2;
        const float wt[4] = {WT0, WT1, WT1, WT0};
        float* const fdb = fd + (size_t)b * Sh * Sh;
        float* const hdb = hd + (size_t)b * Sh * Sh;
        for (int i = tid; i < 2 * TW; i += 256) {
            const int img = i / TW, t2 = i % TW;
            const int r = t2 / (TW / 2), c = t2 % (TW / 2);
            const float* s = img ? sh : sf;
            int lc[4];
#pragma unroll
            for (int kx = 0; kx < 4; ++kx)
                lc[kx] = min(max(bx0 + 2 * c - 1 + kx, 0), S - 1) - bx0 + 2;
            float acc = 0.f;
#pragma unroll
            for (int ky = 0; ky < 4; ++ky) {
                const int lr = min(max(by0 + 2 * r - 1 + ky, 0), S - 1) - by0 + 2;
                const float rs = WT0 * (s[lr * LW + lc[0]] + s[lr * LW + lc[3]])
                               + WT1 * (s[lr * LW + lc[1]] + s[lr * LW + lc[2]]);
                acc = fmaf(wt[ky], rs, acc);
            }
            (img ? hdb : fdb)[((size_t)((by0 >> 1) + r)) * Sh + ((bx0 >> 1) + c)] = acc;
        }
    }

    reduce_and_store(v, scale, tid, wred, &slots[lin]);
}

// ---------------------------------------------------------------------------
// Tail: level-2 loss (512 blocks, tile 64x4 from f2) + level-3 loss
// (128 blocks, L3 tile rebuilt locally from f2 -> no global f3).
// ---------------------------------------------------------------------------
__global__ __launch_bounds__(256, 4) void loss_tail_kernel(
    const float* __restrict__ window,
    const float* __restrict__ rw2, const float* __restrict__ rw3,
    const float* __restrict__ f2, const float* __restrict__ h2,
    double* __restrict__ slots)
{
    __shared__ float smem[5696];   // union: L2 loss 2*544 | L3: p2 4608 + l3 1088
    __shared__ float swin[25];
    __shared__ float wred[4];

    const int tid = threadIdx.x;
    const int tx = tid & 63, ty = tid >> 6;
    if (tid < 25) swin[tid] = window[tid];
    const int lin = blockIdx.x;

    float v, scale;
    if (lin < 512) {
        // level 2: S=128, tile 64x4, PX=1
        const int b = lin >> 6, q = lin & 63;
        const int bx0 = (q & 1) * 64, by0 = (q >> 1) * 4;
        v = bilat_tile<128, 1>(
            f2 + (size_t)b * 16384, h2 + (size_t)b * 16384,
            rw2 + (size_t)b * 25 * 16384,
            smem, smem + 544, swin, bx0, by0, tid);
        scale = 0.25f / (8.f * 128.f * 128.f);
    } else {
        // level 3: S=64, tile 64x4; rebuild L3 tile from f2/h2 in LDS
        const int t = lin - 512;
        const int b = t >> 4, by0 = (t & 15) * 4;
        float* p2 = smem;          // [2][18][128]
        float* l3 = smem + 4608;   // [2][8][68]
        const int fr0 = 2 * by0 - 5;
        for (int i = tid; i < 2 * 18 * 128; i += 256) {
            const int img = i / 2304, j = i % 2304;
            const int r = j >> 7, c = j & 127;
            const int gy = min(max(fr0 + r, 0), 127);
            p2[i] = (img ? h2 : f2)[((size_t)b * 128 + gy) * 128 + c];
        }
        __syncthreads();
        const float wt[4] = {WT0, WT1, WT1, WT0};
        for (int i = tid; i < 2 * 8 * 68; i += 256) {
            const int img = i / 544, j = i % 544;
            const int r = j / 68, c = j % 68;
            const int gy = by0 - 2 + r, gx = c - 2;
            float a = 0.f;
            if ((unsigned)gy < 64u && (unsigned)gx < 64u) {
                int ry[4], cx[4];
#pragma unroll
                for (int k = 0; k < 4; ++k) {
                    ry[k] = min(max(2 * gy - 1 + k, 0), 127) - fr0;
                    cx[k] = min(max(2 * gx - 1 + k, 0), 127);
                }
#pragma unroll
                for (int ky = 0; ky < 4; ++ky) {
                    const float* row = p2 + img * 2304 + ry[ky] * 128;
                    const float rs = WT0 * (row[cx[0]] + row[cx[3]])
                                   + WT1 * (row[cx[1]] + row[cx[2]]);
                    a = fmaf(wt[ky], rs, a);
                }
            }
            l3[i] = a;
        }
        __syncthreads();

        const size_t ks = 64 * 64;
        const float* rwp = rw3 + (size_t)b * 25 * ks + (size_t)(by0 + ty) * 64 + tx;
        float wsum = 0.f, fsv = 0.f, hsv = 0.f;
#pragma unroll
        for (int di = 0; di < 5; ++di) {
#pragma unroll
            for (int dj = 0; dj < 5; ++dj) {
                const int k = di * 5 + dj;
                const float wm = swin[k] * rwp[(size_t)k * ks];
                wsum += wm;
                fsv = fmaf(wm, l3[0 * 544 + (ty + di) * 68 + (tx + dj)], fsv);
                hsv = fmaf(wm, l3[1 * 544 + (ty + di) * 68 + (tx + dj)], hsv);
            }
        }
        const float d = (fsv - hsv) / wsum;
        v = d * d;
        scale = 0.125f / (8.f * 64.f * 64.f);
    }

    reduce_and_store(v, scale, tid, wred, &slots[lin]);
}

__global__ void finalize_kernel(const double* __restrict__ slots, float* __restrict__ out, int n)
{
    __shared__ double dred[4];
    const int t = threadIdx.x;  // 256 threads
    double s = 0.0;
    for (int i = t; i < n; i += 256) s += slots[i];
#pragma unroll
    for (int off = 32; off > 0; off >>= 1) s += __shfl_down(s, off, 64);
    if ((t & 63) == 0) dred[t >> 6] = s;
    __syncthreads();
    if (t == 0) out[0] = (float)(dred[0] + dred[1] + dred[2] + dred[3]);
}

extern "C" void kernel_launch(void* const* d_in, const int* in_sizes, int n_in,
                              void* d_out, int out_size, void* d_ws, size_t ws_size,
                              hipStream_t stream)
{
    const float* fake   = (const float*)d_in[0];
    const float* hdr    = (const float*)d_in[1];
    const float* window = (const float*)d_in[2];
    const float* rw0    = (const float*)d_in[3];
    const float* rw1    = (const float*)d_in[4];
    const float* rw2    = (const float*)d_in[5];
    const float* rw3    = (const float*)d_in[6];
    float* out = (float*)d_out;

    const int B = 8;
    char* ws = (char*)d_ws;
    double* slots = (double*)ws;                 // 3712 doubles, all stored each call
    float* f1 = (float*)(ws + 32768);
    const size_t n1 = (size_t)B * 256 * 256;
    float* h1 = f1 + n1;
    float* f2 = h1 + n1;
    const size_t n2 = (size_t)B * 128 * 128;
    float* h2 = f2 + n2;

    // K1: level-0 loss + f1 build. 2048 blocks, tile 256x4, PX=4.
    loss_down_kernel<512, 4, 1><<<dim3(2048), 256, 0, stream>>>(
        fake, hdr, window, rw0, slots, 1.0f / (8.f * 512.f * 512.f), f1, h1);

    // K2: level-1 loss + f2 build. 1024 blocks, tile 128x4, PX=2, 4 wg/CU.
    loss_down_kernel<256, 2, 4><<<dim3(1024), 256, 0, stream>>>(
        f1, h1, window, rw1, slots + 2048, 0.5f / (8.f * 256.f * 256.f), f2, h2);

    // K3: level-2 (512) + level-3 rebuild (128).
    loss_tail_kernel<<<dim3(640), 256, 0, stream>>>(
        window, rw2, rw3, f2, h2, slots + 3072);

    // K4: final reduction of 3712 slots.
    finalize_kernel<<<1, 256, 0, stream>>>(slots, out, 3712);
}

// Round 11
// 73.757 us; speedup vs baseline: 1.5300x; 1.2134x over previous
//
#include <hip/hip_runtime.h>
#include <hip/hip_bf16.h>

#define WT0 (-0.09375f)
#define WT1 (0.59375f)

// ---------------------------------------------------------------------------
// K1: R6's proven level-k loss + fused bicubic/2 downsample. Tile 256x4,
// 256 threads, 4 px/thread, float4 rw loads, 3D grid, plain launch_bounds
// (NO min-waves arg: R10 showed MINW=1 on the streaming kernel costs ~19us;
// NO nontemporal: R9 showed nt costs ~40us).
// ---------------------------------------------------------------------------
template <int S>
__global__ __launch_bounds__(256) void loss_down_kernel(
    const float* __restrict__ F0, const float* __restrict__ H0,
    const float* __restrict__ window, const float* __restrict__ RW,
    double* __restrict__ slots, float scale,
    float* __restrict__ fd, float* __restrict__ hd)
{
    constexpr int TW = 256;
    __shared__ __align__(16) float sf[8][TW + 4];
    __shared__ __align__(16) float sh[8][TW + 4];
    __shared__ float swin[25];
    __shared__ float wred[4];

    const int tid = threadIdx.x;
    const int tx = tid & 63, ty = tid >> 6;
    if (tid < 25) swin[tid] = window[tid];

    const int bx0 = blockIdx.x * TW;
    const int by0 = blockIdx.y * 4;
    const int b   = blockIdx.z;

    const float* Fb = F0 + (size_t)b * S * S;
    const float* Hb = H0 + (size_t)b * S * S;

    for (int i = tid; i < 8 * (TW + 4); i += 256) {
        const int r = i / (TW + 4), c = i % (TW + 4);
        const int y = by0 + r - 2, x = bx0 + c - 2;
        float fv = 0.f, hv = 0.f;
        if ((unsigned)y < (unsigned)S && (unsigned)x < (unsigned)S) {
            const size_t id = (size_t)y * S + x;
            fv = Fb[id]; hv = Hb[id];
        }
        sf[r][c] = fv; sh[r][c] = hv;
    }
    __syncthreads();

    const int x0 = bx0 + 4 * tx, y = by0 + ty;
    const size_t ks = (size_t)S * S;
    const float* rwp = RW + (size_t)b * 25 * ks + (size_t)y * S + x0;

    float wsum[4] = {0.f, 0.f, 0.f, 0.f};
    float fs[4]   = {0.f, 0.f, 0.f, 0.f};
    float hs[4]   = {0.f, 0.f, 0.f, 0.f};
#pragma unroll
    for (int di = 0; di < 5; ++di) {
        float f9[9], h9[9];
        {
            const float4* pf = (const float4*)&sf[ty + di][4 * tx];
            const float4 a0 = pf[0], a1 = pf[1];
            f9[0]=a0.x; f9[1]=a0.y; f9[2]=a0.z; f9[3]=a0.w;
            f9[4]=a1.x; f9[5]=a1.y; f9[6]=a1.z; f9[7]=a1.w;
            f9[8]=sf[ty + di][4 * tx + 8];
            const float4* ph = (const float4*)&sh[ty + di][4 * tx];
            const float4 b0 = ph[0], b1 = ph[1];
            h9[0]=b0.x; h9[1]=b0.y; h9[2]=b0.z; h9[3]=b0.w;
            h9[4]=b1.x; h9[5]=b1.y; h9[6]=b1.z; h9[7]=b1.w;
            h9[8]=sh[ty + di][4 * tx + 8];
        }
#pragma unroll
        for (int dj = 0; dj < 5; ++dj) {
            const int k = di * 5 + dj;
            const float4 rv = *(const float4*)(rwp + (size_t)k * ks);
            const float w0 = swin[k] * rv.x;
            const float w1 = swin[k] * rv.y;
            const float w2 = swin[k] * rv.z;
            const float w3 = swin[k] * rv.w;
            wsum[0] += w0; wsum[1] += w1; wsum[2] += w2; wsum[3] += w3;
            fs[0] = fmaf(w0, f9[dj + 0], fs[0]);
            fs[1] = fmaf(w1, f9[dj + 1], fs[1]);
            fs[2] = fmaf(w2, f9[dj + 2], fs[2]);
            fs[3] = fmaf(w3, f9[dj + 3], fs[3]);
            hs[0] = fmaf(w0, h9[dj + 0], hs[0]);
            hs[1] = fmaf(w1, h9[dj + 1], hs[1]);
            hs[2] = fmaf(w2, h9[dj + 2], hs[2]);
            hs[3] = fmaf(w3, h9[dj + 3], hs[3]);
        }
    }
    float v = 0.f;
#pragma unroll
    for (int p = 0; p < 4; ++p) {
        const float d = (fs[p] - hs[p]) / wsum[p];
        v = fmaf(d, d, v);
    }
#pragma unroll
    for (int off = 32; off > 0; off >>= 1) v += __shfl_down(v, off, 64);
    if ((tid & 63) == 0) wred[tid >> 6] = v;

    // fused bicubic /2 from the LDS tile (edge-clamped taps)
    {
        constexpr int Sh = S / 2;
        const float wt[4] = {WT0, WT1, WT1, WT0};
        for (int i = tid; i < 512; i += 256) {
            const int img = i >> 8, t2 = i & 255;
            const int r = t2 >> 7, c = t2 & 127;
            const int g1y = (by0 >> 1) + r, g1x = (bx0 >> 1) + c;
            float (*s)[TW + 4] = img ? sh : sf;
            int lc[4];
#pragma unroll
            for (int kx = 0; kx < 4; ++kx)
                lc[kx] = min(max(bx0 + 2 * c - 1 + kx, 0), S - 1) - bx0 + 2;
            float acc = 0.f;
#pragma unroll
            for (int ky = 0; ky < 4; ++ky) {
                const int lr = min(max(by0 + 2 * r - 1 + ky, 0), S - 1) - by0 + 2;
                const float rs = WT0 * (s[lr][lc[0]] + s[lr][lc[3]])
                               + WT1 * (s[lr][lc[1]] + s[lr][lc[2]]);
                acc = fmaf(wt[ky], rs, acc);
            }
            float* dst = img ? hd : fd;
            dst[((size_t)b * Sh + g1y) * Sh + g1x] = acc;
        }
    }

    __syncthreads();
    if (tid == 0) {
        const float sB = wred[0] + wred[1] + wred[2] + wred[3];
        const unsigned lin = blockIdx.x + gridDim.x * (blockIdx.y + gridDim.y * blockIdx.z);
        slots[lin] = (double)sB * (double)scale;
    }
}

// ---------------------------------------------------------------------------
// K2: 1024 blocks, one launch.
//   lin < 512 : level-1 loss + f2/h2 build (exact R6 K2 body, S=256, PX=4).
//   lin >= 512: level-2 loss; block rebuilds its f2 8x68 tile locally from
//     f1/h1 (18x138 stage), so it needs no f2 dependency -> levels 1 and 2
//     stream concurrently. LDS union 24KB; at 1024 blocks (4/CU) LDS is not
//     the occupancy limiter.
// ---------------------------------------------------------------------------
__global__ __launch_bounds__(256) void k2_kernel(
    const float* __restrict__ window,
    const float* __restrict__ rw1, const float* __restrict__ rw2,
    const float* __restrict__ f1, const float* __restrict__ h1,
    float* __restrict__ f2, float* __restrict__ h2,
    double* __restrict__ slots)
{
    __shared__ __align__(16) float smem[6056];  // lvl1: sf 2080 + sh 2080 | lvl2: p1 4968 + l2 1088
    __shared__ float swin[25];
    __shared__ float wred[4];

    const int tid = threadIdx.x;
    const int tx = tid & 63, ty = tid >> 6;
    if (tid < 25) swin[tid] = window[tid];
    const int lin = blockIdx.x;

    float v, scale;
    if (lin < 512) {
        // ---------- level-1 loss + downsample, S=256, tile 256x4 ----------
        constexpr int S = 256, LW = 260;
        const int b = lin >> 6, by0 = (lin & 63) * 4;
        float* sf = smem;
        float* sh = smem + 2080;
        const float* Fb = f1 + (size_t)b * S * S;
        const float* Hb = h1 + (size_t)b * S * S;
        for (int i = tid; i < 8 * LW; i += 256) {
            const int r = i / LW, c = i % LW;
            const int y = by0 + r - 2, x = c - 2;
            float fv = 0.f, hv = 0.f;
            if ((unsigned)y < (unsigned)S && (unsigned)x < (unsigned)S) {
                const size_t id = (size_t)y * S + x;
                fv = Fb[id]; hv = Hb[id];
            }
            sf[r * LW + c] = fv; sh[r * LW + c] = hv;
        }
        __syncthreads();

        const int x0 = 4 * tx, y = by0 + ty;
        const size_t ks = (size_t)S * S;
        const float* rwp = rw1 + (size_t)b * 25 * ks + (size_t)y * S + x0;
        float wsum[4] = {0.f,0.f,0.f,0.f}, fsv[4] = {0.f,0.f,0.f,0.f}, hsv[4] = {0.f,0.f,0.f,0.f};
#pragma unroll
        for (int di = 0; di < 5; ++di) {
            float f9[9], h9[9];
            const int ro = (ty + di) * LW + 4 * tx;
            const float4 a0 = *(const float4*)&sf[ro], a1 = *(const float4*)&sf[ro + 4];
            f9[0]=a0.x; f9[1]=a0.y; f9[2]=a0.z; f9[3]=a0.w;
            f9[4]=a1.x; f9[5]=a1.y; f9[6]=a1.z; f9[7]=a1.w; f9[8]=sf[ro + 8];
            const float4 b0 = *(const float4*)&sh[ro], b1 = *(const float4*)&sh[ro + 4];
            h9[0]=b0.x; h9[1]=b0.y; h9[2]=b0.z; h9[3]=b0.w;
            h9[4]=b1.x; h9[5]=b1.y; h9[6]=b1.z; h9[7]=b1.w; h9[8]=sh[ro + 8];
#pragma unroll
            for (int dj = 0; dj < 5; ++dj) {
                const int k = di * 5 + dj;
                const float4 rv = *(const float4*)(rwp + (size_t)k * ks);
                const float w0 = swin[k] * rv.x, w1 = swin[k] * rv.y;
                const float w2 = swin[k] * rv.z, w3 = swin[k] * rv.w;
                wsum[0] += w0; wsum[1] += w1; wsum[2] += w2; wsum[3] += w3;
                fsv[0] = fmaf(w0, f9[dj + 0], fsv[0]);
                fsv[1] = fmaf(w1, f9[dj + 1], fsv[1]);
                fsv[2] = fmaf(w2, f9[dj + 2], fsv[2]);
                fsv[3] = fmaf(w3, f9[dj + 3], fsv[3]);
                hsv[0] = fmaf(w0, h9[dj + 0], hsv[0]);
                hsv[1] = fmaf(w1, h9[dj + 1], hsv[1]);
                hsv[2] = fmaf(w2, h9[dj + 2], hsv[2]);
                hsv[3] = fmaf(w3, h9[dj + 3], hsv[3]);
            }
        }
        v = 0.f;
#pragma unroll
        for (int p = 0; p < 4; ++p) {
            const float d = (fsv[p] - hsv[p]) / wsum[p];
            v = fmaf(d, d, v);
        }
        scale = 0.5f / (8.f * 256.f * 256.f);

        // fused /2 downsample -> f2/h2 (needed by K3's level-3 rebuild)
        {
            const float wt[4] = {WT0, WT1, WT1, WT0};
            for (int i = tid; i < 512; i += 256) {
                const int img = i >> 8, t2 = i & 255;
                const int r = t2 >> 7, c = t2 & 127;
                const float* s = img ? sh : sf;
                int lc[4];
#pragma unroll
                for (int kx = 0; kx < 4; ++kx)
                    lc[kx] = min(max(2 * c - 1 + kx, 0), S - 1) + 2;
                float acc = 0.f;
#pragma unroll
                for (int ky = 0; ky < 4; ++ky) {
                    const int lr = min(max(by0 + 2 * r - 1 + ky, 0), S - 1) - by0 + 2;
                    const float rs = WT0 * (s[lr * LW + lc[0]] + s[lr * LW + lc[3]])
                                   + WT1 * (s[lr * LW + lc[1]] + s[lr * LW + lc[2]]);
                    acc = fmaf(wt[ky], rs, acc);
                }
                float* dst = img ? h2 : f2;
                dst[((size_t)b * 128 + ((by0 >> 1) + r)) * 128 + c] = acc;
            }
        }
    } else {
        // ---------- level-2 loss, f2 tile rebuilt locally from f1 ----------
        const int t = lin - 512;
        const int b = t >> 6, q = t & 63;
        const int bx0 = (q & 1) * 64, by0 = (q >> 1) * 4;
        float* p1 = smem;           // [2][18][138]
        float* l2 = smem + 4968;    // [2][8][68]
        const int fr0 = 2 * by0 - 5, fc0 = 2 * bx0 - 5;
        const float* F1 = f1 + (size_t)b * 256 * 256;
        const float* H1 = h1 + (size_t)b * 256 * 256;
        for (int i = tid; i < 2 * 18 * 138; i += 256) {
            const int img = i / 2484, j = i % 2484;
            const int r = j / 138, c = j % 138;
            const int gy = min(max(fr0 + r, 0), 255);
            const int gx = min(max(fc0 + c, 0), 255);
            p1[i] = (img ? H1 : F1)[(size_t)gy * 256 + gx];
        }
        __syncthreads();
        const float wt[4] = {WT0, WT1, WT1, WT0};
        for (int i = tid; i < 2 * 8 * 68; i += 256) {
            const int img = i / 544, j = i % 544;
            const int r = j / 68, c = j % 68;
            const int gy = by0 - 2 + r, gx = bx0 - 2 + c;
            float a = 0.f;
            if ((unsigned)gy < 128u && (unsigned)gx < 128u) {
                int ry[4], cx[4];
#pragma unroll
                for (int k = 0; k < 4; ++k) {
                    ry[k] = min(max(2 * gy - 1 + k, 0), 255) - fr0;
                    cx[k] = min(max(2 * gx - 1 + k, 0), 255) - fc0;
                }
#pragma unroll
                for (int ky = 0; ky < 4; ++ky) {
                    const float* row = p1 + img * 2484 + ry[ky] * 138;
                    const float rs = WT0 * (row[cx[0]] + row[cx[3]])
                                   + WT1 * (row[cx[1]] + row[cx[2]]);
                    a = fmaf(wt[ky], rs, a);
                }
            }
            l2[i] = a;
        }
        __syncthreads();

        const size_t ks = 128 * 128;
        const float* rwp = rw2 + (size_t)b * 25 * ks + (size_t)(by0 + ty) * 128 + (bx0 + tx);
        float wsum = 0.f, fsv = 0.f, hsv = 0.f;
#pragma unroll
        for (int di = 0; di < 5; ++di) {
#pragma unroll
            for (int dj = 0; dj < 5; ++dj) {
                const int k = di * 5 + dj;
                const float wm = swin[k] * rwp[(size_t)k * ks];
                wsum += wm;
                fsv = fmaf(wm, l2[0 * 544 + (ty + di) * 68 + (tx + dj)], fsv);
                hsv = fmaf(wm, l2[1 * 544 + (ty + di) * 68 + (tx + dj)], hsv);
            }
        }
        const float d = (fsv - hsv) / wsum;
        v = d * d;
        scale = 0.25f / (8.f * 128.f * 128.f);
    }

#pragma unroll
    for (int off = 32; off > 0; off >>= 1) v += __shfl_down(v, off, 64);
    if ((tid & 63) == 0) wred[tid >> 6] = v;
    __syncthreads();
    if (tid == 0) {
        const float sB = wred[0] + wred[1] + wred[2] + wred[3];
        slots[lin] = (double)sB * (double)scale;
    }
}

// ---------------------------------------------------------------------------
// K3: level-3 loss only (128 blocks). L3 tile rebuilt locally from f2
// (R6's proven pattern) -> no global f3 round-trip.
// ---------------------------------------------------------------------------
__global__ __launch_bounds__(256) void l3_kernel(
    const float* __restrict__ window, const float* __restrict__ rw3,
    const float* __restrict__ f2, const float* __restrict__ h2,
    double* __restrict__ slots)
{
    __shared__ float p2[2 * 18 * 128];
    __shared__ float l3[2 * 8 * 68];
    __shared__ float swin[25];
    __shared__ float wred[4];

    const int tid = threadIdx.x;
    const int tx = tid & 63, ty = tid >> 6;
    if (tid < 25) swin[tid] = window[tid];

    const int t = blockIdx.x;
    const int b = t >> 4, by0 = (t & 15) * 4;
    const int fr0 = 2 * by0 - 5;
    for (int i = tid; i < 2 * 18 * 128; i += 256) {
        const int img = i / 2304, j = i % 2304;
        const int r = j >> 7, c = j & 127;
        const int gy = min(max(fr0 + r, 0), 127);
        p2[i] = (img ? h2 : f2)[((size_t)b * 128 + gy) * 128 + c];
    }
    __syncthreads();
    const float wt[4] = {WT0, WT1, WT1, WT0};
    for (int i = tid; i < 2 * 8 * 68; i += 256) {
        const int img = i / 544, j = i % 544;
        const int r = j / 68, c = j % 68;
        const int gy = by0 - 2 + r, gx = c - 2;
        float a = 0.f;
        if ((unsigned)gy < 64u && (unsigned)gx < 64u) {
            int ry[4], cx[4];
#pragma unroll
            for (int k = 0; k < 4; ++k) {
                ry[k] = min(max(2 * gy - 1 + k, 0), 127) - fr0;
                cx[k] = min(max(2 * gx - 1 + k, 0), 127);
            }
#pragma unroll
            for (int ky = 0; ky < 4; ++ky) {
                const float* row = p2 + img * 2304 + ry[ky] * 128;
                const float rs = WT0 * (row[cx[0]] + row[cx[3]])
                               + WT1 * (row[cx[1]] + row[cx[2]]);
                a = fmaf(wt[ky], rs, a);
            }
        }
        l3[i] = a;
    }
    __syncthreads();

    const size_t ks = 64 * 64;
    const float* rwp = rw3 + (size_t)b * 25 * ks + (size_t)(by0 + ty) * 64 + tx;
    float wsum = 0.f, fsv = 0.f, hsv = 0.f;
#pragma unroll
    for (int di = 0; di < 5; ++di) {
#pragma unroll
        for (int dj = 0; dj < 5; ++dj) {
            const int k = di * 5 + dj;
            const float wm = swin[k] * rwp[(size_t)k * ks];
            wsum += wm;
            fsv = fmaf(wm, l3[0 * 544 + (ty + di) * 68 + (tx + dj)], fsv);
            hsv = fmaf(wm, l3[1 * 544 + (ty + di) * 68 + (tx + dj)], hsv);
        }
    }
    const float d = (fsv - hsv) / wsum;
    float v = d * d;

#pragma unroll
    for (int off = 32; off > 0; off >>= 1) v += __shfl_down(v, off, 64);
    if ((tid & 63) == 0) wred[tid >> 6] = v;
    __syncthreads();
    if (tid == 0) {
        const float sB = wred[0] + wred[1] + wred[2] + wred[3];
        slots[blockIdx.x] = (double)sB * (double)(0.125f / (8.f * 64.f * 64.f));
    }
}

__global__ void finalize_kernel(const double* __restrict__ slots, float* __restrict__ out, int n)
{
    __shared__ double dred[4];
    const int t = threadIdx.x;  // 256 threads
    double s = 0.0;
    for (int i = t; i < n; i += 256) s += slots[i];
#pragma unroll
    for (int off = 32; off > 0; off >>= 1) s += __shfl_down(s, off, 64);
    if ((t & 63) == 0) dred[t >> 6] = s;
    __syncthreads();
    if (t == 0) out[0] = (float)(dred[0] + dred[1] + dred[2] + dred[3]);
}

extern "C" void kernel_launch(void* const* d_in, const int* in_sizes, int n_in,
                              void* d_out, int out_size, void* d_ws, size_t ws_size,
                              hipStream_t stream)
{
    const float* fake   = (const float*)d_in[0];
    const float* hdr    = (const float*)d_in[1];
    const float* window = (const float*)d_in[2];
    const float* rw0    = (const float*)d_in[3];
    const float* rw1    = (const float*)d_in[4];
    const float* rw2    = (const float*)d_in[5];
    const float* rw3    = (const float*)d_in[6];
    float* out = (float*)d_out;

    const int B = 8;
    char* ws = (char*)d_ws;
    double* slots = (double*)ws;                 // 3200 doubles, all stored each call
    float* f1 = (float*)(ws + 32768);
    const size_t n1 = (size_t)B * 256 * 256;
    float* h1 = f1 + n1;
    float* f2 = h1 + n1;
    const size_t n2 = (size_t)B * 128 * 128;
    float* h2 = f2 + n2;

    // K1: level-0 loss + f1 build. 2048 blocks (R6-exact).
    loss_down_kernel<512><<<dim3(2, 128, B), 256, 0, stream>>>(
        fake, hdr, window, rw0, slots, 1.0f / (8.f * 512.f * 512.f), f1, h1);

    // K2: level-1 loss + f2 build (512 blk) MERGED with level-2 loss
    // rebuilding f2 locally from f1 (512 blk). slots[2048..3071].
    k2_kernel<<<dim3(1024), 256, 0, stream>>>(
        window, rw1, rw2, f1, h1, f2, h2, slots + 2048);

    // K3: level-3 only (128 blk). slots[3072..3199].
    l3_kernel<<<dim3(128), 256, 0, stream>>>(
        window, rw3, f2, h2, slots + 3072);

    // K4: final reduction of 3200 slots.
    finalize_kernel<<<1, 256, 0, stream>>>(slots, out, 3200);
}